// Round 1
// baseline (503.048 us; speedup 1.0000x reference)
//
#include <hip/hip_runtime.h>

// GenLSTM: B=8192, T=256 (255 steps), noise=8, seq_dim=4, HID=64, gates=256.
// R6: single-barrier step. rocprof showed all pipes <55% busy at ~3300 cyc/step
// => the 3-barrier/3-LDS-round-trip chain (cell->B1->y1->B2->y2->B3->x->z) was
// latency-bound, not throughput-bound. Now each wave redundantly computes the
// FULL 64-wide MLP for the block's 16 rows (W1/W2/W3 frags in VGPRs, +12
// MFMAs/wave/step), staging y1/y2 in a wave-PRIVATE LDS row: per-wave DS ops
// are in-order, so write->read needs no barrier. Only B1 (h broadcast across
// the 4 column-split gate waves) remains. a2 LDS staging is gone: the slice-2
// operand (x|noise|1) is built in registers (quad0 lanes already hold x in
// their C-frag; noise loaded as per-lane float4 by quads 0/1). Gate bias b is
// folded into a constant-1 input row u[76] -> z accumulators init to 0 (kills
// bzv regs, freeing budget for the MLP weight frags). Keeps: swapped-operand
// MFMA (weights=A, state=B -> C^T), 7-trans cell with inf-safe clamps,
// pipelined gate-h MFMAs for t+1 reusing the y1-phase h frags.

typedef _Float16 h8 __attribute__((ext_vector_type(8)));
typedef __fp16 p2h __attribute__((ext_vector_type(2)));
typedef float f4 __attribute__((ext_vector_type(4)));

#define MFMA(a, b, c) __builtin_amdgcn_mfma_f32_16x16x32_f16(a, b, c, 0, 0, 0)

constexpr int SEQ = 256, STEPS = 255, ND = 8, SD = 4, HID = 64, G4 = 256;
constexpr int HST = 72;  // h/y row stride (f16): 16B-aligned rows

__device__ __forceinline__ void store4h(_Float16* p, f4 v) {
    p2h lo = __builtin_amdgcn_cvt_pkrtz(v[0], v[1]);
    p2h hi = __builtin_amdgcn_cvt_pkrtz(v[2], v[3]);
    float2 st;
    st.x = __builtin_bit_cast(float, lo);
    st.y = __builtin_bit_cast(float, hi);
    *(float2*)p = st;
}

__global__ __launch_bounds__(256, 2) void genlstm_kernel(
    const float* __restrict__ noise, const float* __restrict__ Wx,
    const float* __restrict__ Wh, const float* __restrict__ b,
    const float* __restrict__ W1, const float* __restrict__ b1,
    const float* __restrict__ W2, const float* __restrict__ b2,
    const float* __restrict__ W3, const float* __restrict__ b3,
    float* __restrict__ out)
{
    __shared__ alignas(16) _Float16 Hb[2 * 16 * HST];   // [pb][row][HST] h state
    __shared__ alignas(16) _Float16 Yp[4 * 16 * HST];   // wave-private MLP staging

    const int tid = threadIdx.x, wid = tid >> 6, lane = tid & 63;
    const int col = lane & 15, quad = lane >> 4, q8 = quad * 8;
    const int row0 = blockIdx.x * 16;
    const int n0 = wid * 16 + col;       // gate col for wg frags (wave-split)
    const int wq = wid * 16 + quad * 4;  // h C^T write col base

    // ---- gate weight frags (column-split across waves) ----
    // u index k: [0..63]=h, [64..67]=x, [68..75]=noise, [76]=1 (bias), [77..95]=0
    h8 wg[4][3];
    #pragma unroll
    for (int g = 0; g < 4; ++g)
        #pragma unroll
        for (int s = 0; s < 3; ++s)
            #pragma unroll
            for (int j = 0; j < 8; ++j) {
                const int k = 32 * s + q8 + j;
                const int n = 64 * g + n0;
                float v;
                if (k < 64) v = Wh[k * G4 + n];
                else if (k < 76) v = Wx[(k - 64) * G4 + n];
                else if (k == 76) v = b[n];
                else v = 0.0f;
                wg[g][s][j] = (_Float16)v;
            }
    // ---- full MLP weight frags (per-wave redundant) ----
    h8 w1f[4][2], w2f[4][2], w3f[2];
    #pragma unroll
    for (int tn = 0; tn < 4; ++tn)
        #pragma unroll
        for (int s = 0; s < 2; ++s)
            #pragma unroll
            for (int j = 0; j < 8; ++j) {
                const int k = 32 * s + q8 + j;
                w1f[tn][s][j] = (_Float16)W1[k * HID + 16 * tn + col];
                w2f[tn][s][j] = (_Float16)W2[k * HID + 16 * tn + col];
            }
    #pragma unroll
    for (int s = 0; s < 2; ++s)
        #pragma unroll
        for (int j = 0; j < 8; ++j) {
            const int k = 32 * s + q8 + j;
            w3f[s][j] = (_Float16)(col < 4 ? W3[k * SD + col] : 0.0f);
        }
    // biases by OUTPUT index (C^T): feature m = quad*4 + r within each 16-tile
    f4 b1v[4], b2v[4], b3v;
    #pragma unroll
    for (int r = 0; r < 4; ++r) {
        #pragma unroll
        for (int tn = 0; tn < 4; ++tn) {
            b1v[tn][r] = b1[16 * tn + quad * 4 + r];
            b2v[tn][r] = b2[16 * tn + quad * 4 + r];
        }
        b3v[r] = (quad == 0) ? b3[r] : 0.0f;
    }

    if (tid < 16) {  // out[:,0,:] = 0
        float4 z; z.x = z.y = z.z = z.w = 0.0f;
        *(float4*)(out + (size_t)(row0 + tid) * SEQ * SD) = z;
    }

    // per-lane noise float4: quad0 -> dims 0..3, quad1 -> dims 4..7
    const float* nptr = noise + (size_t)(row0 + col) * SEQ * ND + (quad & 1) * 4;
    float4 nf = {0.f, 0.f, 0.f, 0.f};
    if (quad < 2) nf = *(const float4*)nptr;
    nptr += ND;

    _Float16* Hrow[2] = { &Hb[col * HST], &Hb[(16 + col) * HST] };
    _Float16* Yr = &Yp[(wid * 16 + col) * HST];
    float* outp = out + ((size_t)(row0 + col) * SEQ + 1) * SD;

    const f4 fz = {0.f, 0.f, 0.f, 0.f};
    f4 cst = fz, run = fz, xv = fz;
    // z accumulators persist across iterations; bias arrives via the u[76]=1
    // row in the slice-2 MFMA, so init is plain zero (h(0)=0, x(0)=0).
    f4 zi = fz, zf = fz, zg = fz, zo = fz;
    h8 h0, h1;  // h(t+1) frags, loaded post-B1, reused for gate-h MFMAs

    auto body = [&](int pb) {
        // ---- build slice-2 operand (x|noise|1) in registers, complete z(t) ----
        union { h8 v; p2h p[4]; } a2;
        p2h zz = __builtin_amdgcn_cvt_pkrtz(0.f, 0.f);
        a2.p[0] = a2.p[1] = a2.p[2] = a2.p[3] = zz;
        if (quad == 0) {          // k=64..71: x[0..3], noise[0..3]
            a2.p[0] = __builtin_amdgcn_cvt_pkrtz(xv[0], xv[1]);
            a2.p[1] = __builtin_amdgcn_cvt_pkrtz(xv[2], xv[3]);
            a2.p[2] = __builtin_amdgcn_cvt_pkrtz(nf.x, nf.y);
            a2.p[3] = __builtin_amdgcn_cvt_pkrtz(nf.z, nf.w);
        } else if (quad == 1) {   // k=72..79: noise[4..7], 1 (bias row), 0
            a2.p[0] = __builtin_amdgcn_cvt_pkrtz(nf.x, nf.y);
            a2.p[1] = __builtin_amdgcn_cvt_pkrtz(nf.z, nf.w);
            a2.p[2] = __builtin_amdgcn_cvt_pkrtz(1.0f, 0.f);
        }
        zi = MFMA(wg[0][2], a2.v, zi);
        zf = MFMA(wg[1][2], a2.v, zf);
        zg = MFMA(wg[2][2], a2.v, zg);
        zo = MFMA(wg[3][2], a2.v, zo);

        // prefetch noise(t+1) (t+1 <= 255 always in-bounds)
        if (quad < 2) nf = *(const float4*)nptr;
        nptr += ND;

        // ---- cell update, 7 transcendentals (shared denom, inf-safe clamps) ----
        f4 hv;
        #pragma unroll
        for (int r = 0; r < 4; ++r) {
            float Ei = __expf(-fmaxf(zi[r], -15.f));
            float Ef = __expf(-fmaxf(zf[r], -15.f));
            float Eg = __expf(-2.f * fmaxf(zg[r], -15.f));
            float Eo = __expf(-zo[r]);
            float Di = 1.f + Ei, Df = 1.f + Ef, Dg = 1.f + Eg, Do = 1.f + Eo;
            float DiDg = Di * Dg;
            float cn = (cst[r] * DiDg + (2.f - Dg) * Df) *
                       __builtin_amdgcn_rcpf(Df * DiDg);
            cst[r] = cn;
            float Ec = __expf(-2.f * fmaxf(cn, -15.f));
            hv[r] = (1.f - Ec) * __builtin_amdgcn_rcpf(Do * (1.f + Ec));
        }
        store4h(Hrow[pb ^ 1] + wq, hv);  // h(t+1)
        __syncthreads();  // B1 -- the only barrier per step

        const _Float16* hb = Hrow[pb ^ 1];
        h0 = *(const h8*)(hb + q8);
        h1 = *(const h8*)(hb + 32 + q8);

        // ---- y1 = relu(h @ W1 + b1), full 64 cols per wave ----
        #pragma unroll
        for (int tn = 0; tn < 4; ++tn) {
            f4 a = b1v[tn];
            a = MFMA(w1f[tn][0], h0, a);
            a = MFMA(w1f[tn][1], h1, a);
            #pragma unroll
            for (int r = 0; r < 4; ++r) a[r] = fmaxf(a[r], 0.f);
            store4h(Yr + 16 * tn + 4 * quad, a);
        }

        // gate-h MFMAs for t+1 overlap the y1 write->read LDS latency
        zi = fz; zi = MFMA(wg[0][0], h0, zi); zi = MFMA(wg[0][1], h1, zi);
        zf = fz; zf = MFMA(wg[1][0], h0, zf); zf = MFMA(wg[1][1], h1, zf);
        zg = fz; zg = MFMA(wg[2][0], h0, zg); zg = MFMA(wg[2][1], h1, zg);
        zo = fz; zo = MFMA(wg[3][0], h0, zo); zo = MFMA(wg[3][1], h1, zo);

        // ---- y2 = relu(y1 @ W2 + b2) (wave-private round trip, no barrier) ----
        h8 p0 = *(const h8*)(Yr + q8);
        h8 p1 = *(const h8*)(Yr + 32 + q8);
        #pragma unroll
        for (int tn = 0; tn < 4; ++tn) {
            f4 a = b2v[tn];
            a = MFMA(w2f[tn][0], p0, a);
            a = MFMA(w2f[tn][1], p1, a);
            #pragma unroll
            for (int r = 0; r < 4; ++r) a[r] = fmaxf(a[r], 0.f);
            store4h(Yr + 16 * tn + 4 * quad, a);
        }

        // ---- x = y2 @ W3 + b3 (quad0 lanes hold the 4 real features) ----
        h8 q0 = *(const h8*)(Yr + q8);
        h8 q1 = *(const h8*)(Yr + 32 + q8);
        xv = b3v;
        xv = MFMA(w3f[0], q0, xv);
        xv = MFMA(w3f[1], q1, xv);

        if (wid == 0 && quad == 0) {
            run += xv;
            *(f4*)outp = run;        // cumsum output, dwordx4
        }
        outp += SD;
    };

    #pragma unroll 1
    for (int t = 0; t < STEPS - 1; t += 2) {
        body(0);
        body(1);
    }
    body(0);  // t = 254
}

extern "C" void kernel_launch(void* const* d_in, const int* in_sizes, int n_in,
                              void* d_out, int out_size, void* d_ws, size_t ws_size,
                              hipStream_t stream) {
    genlstm_kernel<<<512, 256, 0, stream>>>(
        (const float*)d_in[0], (const float*)d_in[1], (const float*)d_in[2],
        (const float*)d_in[3], (const float*)d_in[4], (const float*)d_in[5],
        (const float*)d_in[6], (const float*)d_in[7], (const float*)d_in[8],
        (const float*)d_in[9], (float*)d_out);
}